// Round 1
// baseline (110.433 us; speedup 1.0000x reference)
//
#include <hip/hip_runtime.h>

typedef _Float16 f16;
typedef __attribute__((ext_vector_type(8))) _Float16 f16x8;
typedef __attribute__((ext_vector_type(4))) float f32x4;
typedef __attribute__((ext_vector_type(4))) unsigned int u32x4;

#define NPTS   (16 * 32768)
#define NBLK   2048
// packed-weight layout in d_ws (bytes); LDS mirrors [0, FRAGS_BYTES)
#define W0P_OFF 0
#define W1P_OFF (16 * 1024)
#define W2P_OFF (48 * 1024)
#define WOP_OFF (80 * 1024)
#define FRAGS_BYTES (84 * 1024)
#define TENC_OFF FRAGS_BYTES          // in ws: 16 batches x 16 f32
#define WS_NEEDED (FRAGS_BYTES + 1024)
#define ACT_OFF FRAGS_BYTES           // in LDS: 4 waves x 16 KB act regions
#define LDS_TOTAL (ACT_OFF + 4 * 16384)

// ---------------- pack kernel: fp32 weights -> f16 MFMA-fragment order ----------------
// frag (kt,nt): lane l, elem j  <->  W[k = 32*kt + 8*(l>>4) + j][n = 16*nt + (l&15)]
__global__ void pack_weights(const float* __restrict__ time, const float* __restrict__ te0,
                             const float* __restrict__ te1, const float* __restrict__ W0,
                             const float* __restrict__ W1, const float* __restrict__ W2,
                             const float* __restrict__ Wout, unsigned char* __restrict__ ws) {
  const int bi = blockIdx.x;
  const int l = threadIdx.x;
  if (bi < 84) {
    const float* W; int kt, nt, kmax, ncols, nmax, obase, fi;
    if (bi < 16)      { W = W0;   fi = bi;      kt = fi >> 3; nt = fi & 7; kmax = 55;  ncols = 128; nmax = 128; obase = W0P_OFF; }
    else if (bi < 48) { W = W1;   fi = bi - 16; kt = fi >> 3; nt = fi & 7; kmax = 128; ncols = 128; nmax = 128; obase = W1P_OFF; }
    else if (bi < 80) { W = W2;   fi = bi - 48; kt = fi >> 3; nt = fi & 7; kmax = 128; ncols = 128; nmax = 128; obase = W2P_OFF; }
    else              { W = Wout; fi = bi - 80; kt = fi;      nt = 0;      kmax = 128; ncols = 1;   nmax = 1;   obase = WOP_OFF; }
    const int n = nt * 16 + (l & 15);
    f16 vals[8] __attribute__((aligned(16)));
#pragma unroll
    for (int j = 0; j < 8; ++j) {
      const int k = kt * 32 + (l >> 4) * 8 + j;
      float v = (k < kmax && n < nmax) ? W[k * ncols + n] : 0.f;
      vals[j] = (f16)v;
    }
    *(u32x4*)(ws + obase + (fi * 64 + l) * 16) = *(const u32x4*)vals;
  } else {
    // time encoding: 16 batches x 16 dims fp32
    const int idx = (bi - 84) * 64 + l;  // 0..255
    const int b = idx >> 4, d = idx & 15;
    const float t = time[b];
    const float* emb; int L, dd;
    if (d < 8) { emb = te0; L = 5;  dd = d; }
    else       { emb = te1; L = 20; dd = d - 8; }
    const float tL = t * (float)L;
    int i = (int)floorf(tL);
    i = i < 0 ? 0 : (i > L - 1 ? L - 1 : i);
    const float wlo = (float)(i + 1) - tL;
    float v = wlo * emb[i * 8 + dd] + (1.f - wlo) * emb[(i + 1) * 8 + dd];
    if (t >= 1.f) v = emb[L * 8 + dd];
    ((float*)(ws + TENC_OFF))[idx] = v;
  }
}

// ---------------- one hidden layer: act(K) @ W -> relu -> act(128) ----------------
// act region: per-wave private, 64 rows. X rows are 128 B (K=64), H rows 256 B (K=128).
// 16B slots XOR-swizzled by (row&7) to avoid bank conflicts on stride-256B reads.
template <int KT, int ROWB>
__device__ __forceinline__ void mlp_layer(const char* __restrict__ ldsw, char* __restrict__ act,
                                          const float* __restrict__ bias, int lane) {
  const int g = lane >> 4, r16 = lane & 15;
  f32x4 acc[4][8];
#pragma unroll
  for (int mt = 0; mt < 4; ++mt)
#pragma unroll
    for (int nt = 0; nt < 8; ++nt) acc[mt][nt] = (f32x4){0.f, 0.f, 0.f, 0.f};

#pragma unroll
  for (int kt = 0; kt < KT; ++kt) {
    f16x8 a[4];
#pragma unroll
    for (int mt = 0; mt < 4; ++mt) {
      const int lp = mt * 16 + r16;
      a[mt] = *(const f16x8*)(act + lp * ROWB + (((4 * kt + g) ^ (lp & 7)) * 16));
    }
#pragma unroll
    for (int nt = 0; nt < 8; ++nt) {
      const f16x8 b = *(const f16x8*)(ldsw + ((kt * 8 + nt) * 64 + lane) * 16);
#pragma unroll
      for (int mt = 0; mt < 4; ++mt)
        acc[mt][nt] = __builtin_amdgcn_mfma_f32_16x16x32_f16(a[mt], b, acc[mt][nt], 0, 0, 0);
    }
  }
  // bias + relu + write H back (row stride 256 B)
#pragma unroll
  for (int nt = 0; nt < 8; ++nt) {
    const float bv = bias[nt * 16 + r16];
    const int k = nt * 16 + r16;
    const int slot = k >> 3;
    const int off = (k & 7) * 2;
#pragma unroll
    for (int mt = 0; mt < 4; ++mt) {
#pragma unroll
      for (int rr = 0; rr < 4; ++rr) {
        const int lp = mt * 16 + 4 * g + rr;
        const float v = fmaxf(acc[mt][nt][rr] + bv, 0.f);
        *(f16*)(act + lp * 256 + ((slot ^ (lp & 7)) * 16) + off) = (f16)v;
      }
    }
  }
}

// ---------------- fused main kernel ----------------
__global__ void __launch_bounds__(256, 1)
mlp_main(const float* __restrict__ xyz, const float* __restrict__ b0,
         const float* __restrict__ b1, const float* __restrict__ b2,
         const float* __restrict__ bout, const unsigned char* __restrict__ ws,
         float* __restrict__ out) {
  extern __shared__ char lds[];
  const int tid = threadIdx.x;
  const int lane = tid & 63;
  const int wv = tid >> 6;
  const int bi = blockIdx.x;

  // ---- load this thread's point early (overlaps with staging) ----
  const int p = bi * 256 + tid;
  const float x0 = xyz[p * 3 + 0];
  const float y0 = xyz[p * 3 + 1];
  const float z0 = xyz[p * 3 + 2];

  // ---- stage packed weights global -> LDS ----
  for (int i = tid; i < FRAGS_BYTES / 16; i += 256)
    *(u32x4*)(lds + i * 16) = *(const u32x4*)(ws + i * 16);

  // ---- compute 64-dim feature row into own act region ----
  f16 feat[64] __attribute__((aligned(16)));
  const float* tenc = (const float*)(ws + TENC_OFF) + (bi >> 7) * 16;  // batch = bi/128
#pragma unroll
  for (int i = 0; i < 16; ++i) feat[i] = (f16)tenc[i];
  const float pc0 = (x0 + 1.f) * 0.5f;
  const float pc1 = (y0 + 1.f) * 0.5f;
  const float pc2 = (z0 + 1.f) * 0.5f;
  const float pcs[3] = {pc0, pc1, pc2};
#pragma unroll
  for (int c = 0; c < 3; ++c) {
    feat[16 + c] = (f16)pcs[c];
    float s = __sinf(pcs[c]);
    float co = __cosf(pcs[c]);
#pragma unroll
    for (int f = 0; f < 6; ++f) {
      feat[19 + f * 3 + c] = (f16)s;
      feat[37 + f * 3 + c] = (f16)co;
      const float s2 = 2.f * s * co;       // sin(2x)
      const float c2 = 1.f - 2.f * s * s;  // cos(2x)
      s = s2; co = c2;
    }
  }
#pragma unroll
  for (int i = 55; i < 64; ++i) feat[i] = (f16)0.f;

  char* act = lds + ACT_OFF + wv * 16384;
  const int lp = tid & 63;
#pragma unroll
  for (int s = 0; s < 8; ++s) {
    const int ss = s ^ (lp & 7);
    *(u32x4*)(act + lp * 128 + ss * 16) = *(const u32x4*)&feat[s * 8];
  }

  __syncthreads();  // weights staged; act regions are per-wave private after this

  mlp_layer<2, 128>(lds + W0P_OFF, act, b0, lane);
  mlp_layer<4, 256>(lds + W1P_OFF, act, b1, lane);
  mlp_layer<4, 256>(lds + W2P_OFF, act, b2, lane);

  // ---- output layer: K=128 -> 1 col (padded to 16) ----
  const int g = lane >> 4, r16 = lane & 15;
  f32x4 accO[4];
#pragma unroll
  for (int mt = 0; mt < 4; ++mt) accO[mt] = (f32x4){0.f, 0.f, 0.f, 0.f};
#pragma unroll
  for (int kt = 0; kt < 4; ++kt) {
    const f16x8 bfrag = *(const f16x8*)(lds + WOP_OFF + (kt * 64 + lane) * 16);
#pragma unroll
    for (int mt = 0; mt < 4; ++mt) {
      const int lpp = mt * 16 + r16;
      const f16x8 a = *(const f16x8*)(act + lpp * 256 + (((4 * kt + g) ^ (lpp & 7)) * 16));
      accO[mt] = __builtin_amdgcn_mfma_f32_16x16x32_f16(a, bfrag, accO[mt], 0, 0, 0);
    }
  }
  const float bo = bout[0];
  if (r16 == 0) {
#pragma unroll
    for (int mt = 0; mt < 4; ++mt) {
      float4 o;
      o.x = accO[mt][0] + bo;
      o.y = accO[mt][1] + bo;
      o.z = accO[mt][2] + bo;
      o.w = accO[mt][3] + bo;
      *(float4*)(out + bi * 256 + wv * 64 + mt * 16 + 4 * g) = o;
    }
  }
}

extern "C" void kernel_launch(void* const* d_in, const int* in_sizes, int n_in,
                              void* d_out, int out_size, void* d_ws, size_t ws_size,
                              hipStream_t stream) {
  const float* time = (const float*)d_in[0];
  const float* xyz  = (const float*)d_in[1];
  const float* te0  = (const float*)d_in[2];
  const float* te1  = (const float*)d_in[3];
  const float* W0   = (const float*)d_in[4];
  const float* b0   = (const float*)d_in[5];
  const float* W1   = (const float*)d_in[6];
  const float* b1   = (const float*)d_in[7];
  const float* W2   = (const float*)d_in[8];
  const float* b2   = (const float*)d_in[9];
  const float* Wout = (const float*)d_in[10];
  const float* bout = (const float*)d_in[11];
  float* out = (float*)d_out;
  unsigned char* ws = (unsigned char*)d_ws;
  if (ws_size < WS_NEEDED) return;

  hipFuncSetAttribute((const void*)mlp_main,
                      hipFuncAttributeMaxDynamicSharedMemorySize, LDS_TOTAL);

  pack_weights<<<88, 64, 0, stream>>>(time, te0, te1, W0, W1, W2, Wout, ws);
  mlp_main<<<NBLK, 256, LDS_TOTAL, stream>>>(xyz, b0, b1, b2, bout, ws, out);
}

// Round 2
// 52.808 us; speedup vs baseline: 2.0912x; 2.0912x over previous
//
#include <hip/hip_runtime.h>

typedef _Float16 f16;
typedef __attribute__((ext_vector_type(8))) _Float16 f16x8;
typedef __attribute__((ext_vector_type(4))) float f32x4;
typedef __attribute__((ext_vector_type(4))) unsigned int u32x4;

#define NPTS   (16 * 32768)
#define NTILES 1024          // 512 points per tile
// packed-weight layout in d_ws (bytes); LDS mirrors [0, FRAGS_BYTES)
#define W0P_OFF 0
#define W1P_OFF (16 * 1024)
#define W2P_OFF (48 * 1024)
#define WOP_OFF (80 * 1024)
#define FRAGS_BYTES (84 * 1024)
#define TENC_OFF FRAGS_BYTES          // in ws: 16 batches x 16 f32
#define WS_NEEDED (FRAGS_BYTES + 1024)
#define SCR_OFF FRAGS_BYTES           // in LDS: 8 waves x 8 KB transpose scratch
#define LDS_TOTAL (SCR_OFF + 8 * 8192)  // 148 KB

// ---------------- pack kernel: weights -> f16 A-operand fragments (W^T) ----------------
// A frag (mt,kt): lane l, elem j <-> W_sw[m = 16mt + (l&15)][k] = W[k][m]
//   layer0 (natural k-map, matches layer-0 B build): k = 32kt + 8*(l>>4) + j
//   layers 1,2,out (chained from D layout):          k = 32kt + 16*(j>>2) + 4*(l>>4) + (j&3)
__global__ void pack_weights(const float* __restrict__ time, const float* __restrict__ te0,
                             const float* __restrict__ te1, const float* __restrict__ W0,
                             const float* __restrict__ W1, const float* __restrict__ W2,
                             const float* __restrict__ Wout, unsigned char* __restrict__ ws) {
  const int bi = blockIdx.x;
  const int l = threadIdx.x;
  const int g = l >> 4, r16 = l & 15;
  if (bi < 84) {
    const float* W; int obase, fi, kt, mt, kmax; bool natural, outcol;
    if (bi < 16)      { W = W0;   fi = bi;      mt = fi >> 1; kt = fi & 1; obase = W0P_OFF; kmax = 55;  natural = true;  outcol = false; }
    else if (bi < 48) { W = W1;   fi = bi - 16; mt = fi >> 2; kt = fi & 3; obase = W1P_OFF; kmax = 128; natural = false; outcol = false; }
    else if (bi < 80) { W = W2;   fi = bi - 48; mt = fi >> 2; kt = fi & 3; obase = W2P_OFF; kmax = 128; natural = false; outcol = false; }
    else              { W = Wout; fi = bi - 80; mt = 0;       kt = fi;     obase = WOP_OFF; kmax = 128; natural = false; outcol = true;  }
    const int m = mt * 16 + r16;
    f16 vals[8] __attribute__((aligned(16)));
#pragma unroll
    for (int j = 0; j < 8; ++j) {
      const int k = natural ? (kt * 32 + g * 8 + j)
                            : (kt * 32 + (j >> 2) * 16 + g * 4 + (j & 3));
      float v = 0.f;
      if (k < kmax) v = outcol ? ((m == 0) ? Wout[k] : 0.f) : W[k * 128 + m];
      vals[j] = (f16)v;
    }
    *(u32x4*)(ws + obase + (fi * 64 + l) * 16) = *(const u32x4*)vals;
  } else {
    // time encoding: 16 batches x 16 dims fp32
    const int idx = (bi - 84) * 64 + l;  // 0..255
    const int b = idx >> 4, d = idx & 15;
    const float t = time[b];
    const float* emb; int L, dd;
    if (d < 8) { emb = te0; L = 5;  dd = d; }
    else       { emb = te1; L = 20; dd = d - 8; }
    const float tL = t * (float)L;
    int i = (int)floorf(tL);
    i = i < 0 ? 0 : (i > L - 1 ? L - 1 : i);
    const float wlo = (float)(i + 1) - tL;
    float v = wlo * emb[i * 8 + dd] + (1.f - wlo) * emb[(i + 1) * 8 + dd];
    if (t >= 1.f) v = emb[L * 8 + dd];
    ((float*)(ws + TENC_OFF))[idx] = v;
  }
}

// ---------------- one swapped hidden layer: D = W_sw(128xK) * Bin(Kx64) ----------------
// Bias folded into the MFMA C-init (D: lane col = point, row = 16mt + 4g + r).
// Bout[mtp][nt] elem j := relu(acc[ mt=2mtp+(j>>2) ][nt][ r=j&3 ])  -> matches kperm.
template <int KT>
__device__ __forceinline__ void layer_swapped(const char* __restrict__ wlds,
                                              const float* __restrict__ bias,
                                              const f16x8 (&Bin)[KT][4], f16x8 (&Bout)[4][4],
                                              int lane) {
  const int g4 = (lane >> 4) * 4;
#pragma unroll
  for (int mtp = 0; mtp < 4; ++mtp) {
    const float4 ba = *(const float4*)(bias + mtp * 32 + g4);
    const float4 bb = *(const float4*)(bias + mtp * 32 + 16 + g4);
    f32x4 acc[2][4];
#pragma unroll
    for (int nt = 0; nt < 4; ++nt) {
      acc[0][nt] = (f32x4){ba.x, ba.y, ba.z, ba.w};
      acc[1][nt] = (f32x4){bb.x, bb.y, bb.z, bb.w};
    }
#pragma unroll
    for (int kt = 0; kt < KT; ++kt) {
      const f16x8 A0 = *(const f16x8*)(wlds + (((2 * mtp)     * KT + kt) * 64 + lane) * 16);
      const f16x8 A1 = *(const f16x8*)(wlds + (((2 * mtp + 1) * KT + kt) * 64 + lane) * 16);
#pragma unroll
      for (int nt = 0; nt < 4; ++nt)
        acc[0][nt] = __builtin_amdgcn_mfma_f32_16x16x32_f16(A0, Bin[kt][nt], acc[0][nt], 0, 0, 0);
#pragma unroll
      for (int nt = 0; nt < 4; ++nt)
        acc[1][nt] = __builtin_amdgcn_mfma_f32_16x16x32_f16(A1, Bin[kt][nt], acc[1][nt], 0, 0, 0);
    }
#pragma unroll
    for (int nt = 0; nt < 4; ++nt) {
      f16 tmp[8] __attribute__((aligned(16)));
#pragma unroll
      for (int r = 0; r < 4; ++r) {
        tmp[r]     = (f16)fmaxf(acc[0][nt][r], 0.f);
        tmp[4 + r] = (f16)fmaxf(acc[1][nt][r], 0.f);
      }
      Bout[mtp][nt] = *(const f16x8*)tmp;
    }
  }
}

// ---------------- fused main kernel: persistent blocks, 512 thr, 64 pts/wave ----------------
__global__ void __launch_bounds__(512, 2)
mlp_main(const float* __restrict__ xyz, const float* __restrict__ b0,
         const float* __restrict__ b1, const float* __restrict__ b2,
         const float* __restrict__ bout, const unsigned char* __restrict__ ws,
         float* __restrict__ out) {
  extern __shared__ char lds[];
  const int tid = threadIdx.x;
  const int lane = tid & 63, wv = tid >> 6;
  const int g = lane >> 4, r16 = lane & 15;

  // stage packed weights global -> LDS (once per persistent block)
  for (int i = tid; i < FRAGS_BYTES / 16; i += 512)
    *(u32x4*)(lds + i * 16) = *(const u32x4*)(ws + i * 16);
  __syncthreads();

  char* scr = lds + SCR_OFF + wv * 8192;  // per-wave private transpose scratch
  const float bo = bout[0];

  for (int tile = blockIdx.x; tile < NTILES; tile += gridDim.x) {
    const int pbase = tile * 512 + wv * 64;
    const int p = pbase + lane;

    // ---- 64-dim feature row for own point ----
    f16 feat[64] __attribute__((aligned(16)));
    const float* tb = (const float*)(ws + TENC_OFF) + (tile >> 6) * 16;  // batch = tile/64
#pragma unroll
    for (int i = 0; i < 16; ++i) feat[i] = (f16)tb[i];
    const float xs0 = xyz[p * 3], xs1 = xyz[p * 3 + 1], xs2 = xyz[p * 3 + 2];
    const float pcs[3] = {(xs0 + 1.f) * 0.5f, (xs1 + 1.f) * 0.5f, (xs2 + 1.f) * 0.5f};
#pragma unroll
    for (int c = 0; c < 3; ++c) {
      feat[16 + c] = (f16)pcs[c];
      float s = __sinf(pcs[c]), co = __cosf(pcs[c]);
#pragma unroll
      for (int f = 0; f < 6; ++f) {
        feat[19 + f * 3 + c] = (f16)s;
        feat[37 + f * 3 + c] = (f16)co;
        const float s2 = 2.f * s * co, c2 = 1.f - 2.f * s * s;
        s = s2; co = c2;
      }
    }
#pragma unroll
    for (int i = 55; i < 64; ++i) feat[i] = (f16)0.f;

    // ---- transpose through per-wave scratch: row = point, XOR-swizzled 16B slots ----
#pragma unroll
    for (int s = 0; s < 8; ++s)
      *(u32x4*)(scr + lane * 128 + ((s ^ (lane & 7)) * 16)) = ((const u32x4*)feat)[s];

    f16x8 B0[2][4];
#pragma unroll
    for (int kt = 0; kt < 2; ++kt)
#pragma unroll
      for (int nt = 0; nt < 4; ++nt) {
        const int row = nt * 16 + r16;
        B0[kt][nt] = *(const f16x8*)(scr + row * 128 + (((4 * kt + g) ^ (row & 7)) * 16));
      }

    // ---- 3 hidden layers fully in registers ----
    f16x8 Bx[4][4], By[4][4];
    layer_swapped<2>((const char*)lds + W0P_OFF, b0, B0, Bx, lane);
    layer_swapped<4>((const char*)lds + W1P_OFF, b1, Bx, By, lane);
    layer_swapped<4>((const char*)lds + W2P_OFF, b2, By, Bx, lane);

    // ---- output layer (M=16 padded, only row 0 real) ----
    f32x4 accO[4];
#pragma unroll
    for (int nt = 0; nt < 4; ++nt) accO[nt] = (f32x4){bo, bo, bo, bo};
#pragma unroll
    for (int kt = 0; kt < 4; ++kt) {
      const f16x8 A = *(const f16x8*)((const char*)lds + WOP_OFF + (kt * 64 + lane) * 16);
#pragma unroll
      for (int nt = 0; nt < 4; ++nt)
        accO[nt] = __builtin_amdgcn_mfma_f32_16x16x32_f16(A, Bx[kt][nt], accO[nt], 0, 0, 0);
    }
    if (lane < 16) {
#pragma unroll
      for (int nt = 0; nt < 4; ++nt)
        out[pbase + nt * 16 + lane] = accO[nt][0];
    }
  }
}

extern "C" void kernel_launch(void* const* d_in, const int* in_sizes, int n_in,
                              void* d_out, int out_size, void* d_ws, size_t ws_size,
                              hipStream_t stream) {
  const float* time = (const float*)d_in[0];
  const float* xyz  = (const float*)d_in[1];
  const float* te0  = (const float*)d_in[2];
  const float* te1  = (const float*)d_in[3];
  const float* W0   = (const float*)d_in[4];
  const float* b0   = (const float*)d_in[5];
  const float* W1   = (const float*)d_in[6];
  const float* b1   = (const float*)d_in[7];
  const float* W2   = (const float*)d_in[8];
  const float* b2   = (const float*)d_in[9];
  const float* Wout = (const float*)d_in[10];
  const float* bout = (const float*)d_in[11];
  float* out = (float*)d_out;
  unsigned char* ws = (unsigned char*)d_ws;
  if (ws_size < WS_NEEDED) return;

  hipFuncSetAttribute((const void*)mlp_main,
                      hipFuncAttributeMaxDynamicSharedMemorySize, LDS_TOTAL);

  pack_weights<<<88, 64, 0, stream>>>(time, te0, te1, W0, W1, W2, Wout, ws);
  mlp_main<<<256, 512, LDS_TOTAL, stream>>>(xyz, b0, b1, b2, bout, ws, out);
}